// Round 1
// baseline (9959.147 us; speedup 1.0000x reference)
//
#include <hip/hip_runtime.h>
#include <math.h>

#define NCHUNK 22
#define SEQLEN 600
#define BN_EPS 1e-5f

// ws float offsets
#define OFF_W2T   0          // 13312  : w2 transposed [ci][k][co]
#define OFF_W3R   13312      // 51200  : w3 transposed [j=q*32+ci][co]
#define OFF_WQT   64512      // 32768  : Wq transposed [h][d][e]
#define OFF_WKT   97280      // 32768
#define OFF_WVT   130048     // 32768
#define OFF_WFCT  162816     // 32768  : Wfc transposed [j][d]
#define OFF_WOUTT 195584     // 4096   : Wout transposed [k][d]
#define OFF_FEAT  200704     // 2*B*22*64

__device__ __forceinline__ float swishf(float z) {
    return z / (1.f + __expf(-z));
}

__global__ __launch_bounds__(256) void repack_kernel(
    const float* __restrict__ w2, const float* __restrict__ w3,
    const float* __restrict__ Wq, const float* __restrict__ Wk, const float* __restrict__ Wv,
    const float* __restrict__ Wfc, const float* __restrict__ Wout,
    float* __restrict__ ws)
{
    int tid = blockIdx.x * 256 + threadIdx.x;
    if (tid < 13312) {                       // w2t[(ci*26+k)*32+co] = w2[co][ci][k]
        int co = tid & 31, r = tid >> 5;
        int ci = r / 26, k = r - ci * 26;
        ws[OFF_W2T + tid] = w2[co * 416 + ci * 26 + k];
    }
    int t2 = tid - 13312;
    if (t2 >= 0 && t2 < 51200) {             // w3r[j*64+co] = w3[co][ci][q], j=q*32+ci
        int co = t2 & 63, j = t2 >> 6;
        int q = j >> 5, ci = j & 31;
        ws[OFF_W3R + t2] = w3[co * 800 + ci * 25 + q];
    }
    int t3 = tid - 64512;
    if (t3 >= 0 && t3 < 32768) {             // wqT[(h*64+d)*64+e] = Wq[h][e][d]
        int e = t3 & 63, hd = t3 >> 6;
        int d = hd & 63, h = hd >> 6;
        ws[OFF_WQT + t3] = Wq[h * 4096 + e * 64 + d];
        ws[OFF_WKT + t3] = Wk[h * 4096 + e * 64 + d];
        ws[OFF_WVT + t3] = Wv[h * 4096 + e * 64 + d];
    }
    int t4 = tid - 97280;
    if (t4 >= 0 && t4 < 32768) {             // wfcT[j*64+d] = Wfc[d][j]
        int d = t4 & 63, j = t4 >> 6;
        ws[OFF_WFCT + t4] = Wfc[d * 512 + j];
    }
    int t5 = tid - 130048;
    if (t5 >= 0 && t5 < 4096) {              // woutT[k*64+d] = Wout[d][k]
        int d = t5 & 63, k = t5 >> 6;
        ws[OFF_WOUTT + t5] = Wout[d * 64 + k];
    }
}

// One block = one 4-chunk tile of one sequence (tile 5 has 2 chunks).
// conv1 deduped across the tile's overlapping chunks; conv2 register-tiled
// (4 co per thread, float4 weights); conv3 split-K across the 4 waves so
// w3 (205 KB) streams from L2 exactly once per block.
__global__ __launch_bounds__(256) void encoder_kernel(
    const float* __restrict__ audio1, const float* __restrict__ audio2,
    const float* __restrict__ w1,
    const float* __restrict__ b1, const float* __restrict__ g1, const float* __restrict__ be1,
    const float* __restrict__ m1, const float* __restrict__ v1,
    const float* __restrict__ b2, const float* __restrict__ g2, const float* __restrict__ be2,
    const float* __restrict__ m2, const float* __restrict__ v2,
    const float* __restrict__ b3, const float* __restrict__ g3, const float* __restrict__ be3,
    const float* __restrict__ m3, const float* __restrict__ v3,
    float* __restrict__ ws, int B)
{
    __shared__ float a_s[150];
    __shared__ float w1_s[416];
    __shared__ float A_s[112], Bc_s[112];   // folded BN: y = conv*A + Bc
    __shared__ float y1_s[125 * 17];        // [p][ci], pad 17 to break bank conflicts
    __shared__ float y2_s[4 * 800];         // [cc][q'*32+ci]
    __shared__ float red_s[16 * 64];        // conv3 partials [part*4+cc][co]

    int t = threadIdx.x;
    int blk = blockIdx.x;
    int seq = blk / 6, tile = blk - seq * 6;
    int tc = (tile == 5) ? 2 : 4;           // chunks in this tile
    int nq = 25 * tc;                       // conv2 output positions (tile-relative)
    int ny1 = nq + 25;                      // conv1 output positions needed
    int na = nq + 50;                       // audio samples needed

    const float* audio = (seq < B ? audio1 + (size_t)seq * SEQLEN
                                  : audio2 + (size_t)(seq - B) * SEQLEN) + tile * 100;
    if (t < na) a_s[t] = audio[t];
    for (int i = t; i < 416; i += 256) w1_s[i] = w1[i];
    if (t < 16)       { float A = g1[t] * rsqrtf(v1[t] + BN_EPS); A_s[t] = A; Bc_s[t] = (b1[t] - m1[t]) * A + be1[t]; }
    else if (t < 48)  { int i = t - 16; float A = g2[i] * rsqrtf(v2[i] + BN_EPS); A_s[t] = A; Bc_s[t] = (b2[i] - m2[i]) * A + be2[i]; }
    else if (t < 112) { int i = t - 48; float A = g3[i] * rsqrtf(v3[i] + BN_EPS); A_s[t] = A; Bc_s[t] = (b3[i] - m3[i]) * A + be3[i]; }
    // zero unused y2 region for the tail tile (conv3 reads all 4 cc slots)
    for (int i = t + nq * 32; i < 3200; i += 256) y2_s[i] = 0.f;
    __syncthreads();

    // ---- conv1 + bn + swish -> y1_s ----
    for (int o = t; o < ny1 * 16; o += 256) {
        int p = o >> 4, ci = o & 15;
        float acc = 0.f;
        #pragma unroll
        for (int k = 0; k < 26; ++k) acc = fmaf(a_s[p + k], w1_s[ci * 26 + k], acc);
        float z = fmaf(acc, A_s[ci], Bc_s[ci]);
        y1_s[p * 17 + ci] = swishf(z);
    }
    __syncthreads();

    // ---- conv2 + bn + swish -> y2_s ----
    {
        const float4* w2t4 = (const float4*)(ws + OFF_W2T);
        int cg = t & 7, qb = t >> 3;
        int co0 = cg * 4;
        for (int q = qb; q < nq; q += 32) {
            float ax = 0.f, ay = 0.f, az = 0.f, aw = 0.f;
            for (int ci = 0; ci < 16; ++ci) {
                #pragma unroll
                for (int k = 0; k < 26; ++k) {
                    float yv = y1_s[(q + k) * 17 + ci];
                    float4 w = w2t4[(ci * 26 + k) * 8 + cg];
                    ax = fmaf(yv, w.x, ax);
                    ay = fmaf(yv, w.y, ay);
                    az = fmaf(yv, w.z, az);
                    aw = fmaf(yv, w.w, aw);
                }
            }
            float4 r;
            float z0 = fmaf(ax, A_s[16 + co0 + 0], Bc_s[16 + co0 + 0]); r.x = swishf(z0);
            float z1 = fmaf(ay, A_s[16 + co0 + 1], Bc_s[16 + co0 + 1]); r.y = swishf(z1);
            float z2 = fmaf(az, A_s[16 + co0 + 2], Bc_s[16 + co0 + 2]); r.z = swishf(z2);
            float z3 = fmaf(aw, A_s[16 + co0 + 3], Bc_s[16 + co0 + 3]); r.w = swishf(z3);
            *(float4*)&y2_s[q * 32 + co0] = r;
        }
    }
    __syncthreads();

    // ---- conv3 split-K: wave `part` handles j in [part*200, part*200+200) ----
    {
        const float* w3r = ws + OFF_W3R;
        int part = t >> 6, co = t & 63;
        const float* wp = w3r + (size_t)(part * 200) * 64 + co;
        int jbase = part * 200;
        float acc0 = 0.f, acc1 = 0.f, acc2 = 0.f, acc3 = 0.f;
        for (int i = 0; i < 200; i += 4) {
            float w0 = wp[(i + 0) * 64];
            float w1v = wp[(i + 1) * 64];
            float w2v = wp[(i + 2) * 64];
            float w3v = wp[(i + 3) * 64];
            float4 ya = *(const float4*)&y2_s[0 * 800 + jbase + i];
            float4 yb = *(const float4*)&y2_s[1 * 800 + jbase + i];
            float4 yc = *(const float4*)&y2_s[2 * 800 + jbase + i];
            float4 yd = *(const float4*)&y2_s[3 * 800 + jbase + i];
            acc0 = fmaf(ya.x, w0, fmaf(ya.y, w1v, fmaf(ya.z, w2v, fmaf(ya.w, w3v, acc0))));
            acc1 = fmaf(yb.x, w0, fmaf(yb.y, w1v, fmaf(yb.z, w2v, fmaf(yb.w, w3v, acc1))));
            acc2 = fmaf(yc.x, w0, fmaf(yc.y, w1v, fmaf(yc.z, w2v, fmaf(yc.w, w3v, acc2))));
            acc3 = fmaf(yd.x, w0, fmaf(yd.y, w1v, fmaf(yd.z, w2v, fmaf(yd.w, w3v, acc3))));
        }
        red_s[(part * 4 + 0) * 64 + co] = acc0;
        red_s[(part * 4 + 1) * 64 + co] = acc1;
        red_s[(part * 4 + 2) * 64 + co] = acc2;
        red_s[(part * 4 + 3) * 64 + co] = acc3;
    }
    __syncthreads();
    {
        int cc = t >> 6, co = t & 63;
        if (cc < tc) {
            float s = red_s[(0 * 4 + cc) * 64 + co] + red_s[(1 * 4 + cc) * 64 + co]
                    + red_s[(2 * 4 + cc) * 64 + co] + red_s[(3 * 4 + cc) * 64 + co];
            float z = fmaf(s, A_s[48 + co], Bc_s[48 + co]);
            ws[OFF_FEAT + ((size_t)(seq * NCHUNK + tile * 4 + cc)) * 64 + co] = swishf(z);
        }
    }
}

// One block per sequence: 8 heads, fc fused into the head loop, then mean + Wout.
__global__ __launch_bounds__(256) void mha_kernel(
    const float* __restrict__ ws,
    const float* __restrict__ bq, const float* __restrict__ bk, const float* __restrict__ bv,
    const float* __restrict__ bfc, const float* __restrict__ bout,
    float* __restrict__ out, int B)
{
    __shared__ float f_s[22 * 64];
    __shared__ float q_s[22 * 64];
    __shared__ float k_s[22 * 65];   // pad 65: stride-64 reads in QK^T would be 1-bank
    __shared__ float v_s[22 * 64];
    __shared__ float s_s[22 * 22];
    __shared__ float o_s[22 * 64];
    __shared__ float fc_s[22 * 64];
    __shared__ float mean_s[64];

    int t = threadIdx.x;
    int b = blockIdx.x;
    const float* feat = ws + OFF_FEAT + (size_t)b * 22 * 64;
    for (int i = t; i < 1408; i += 256) f_s[i] = feat[i];
    __syncthreads();

    const float* wqT = ws + OFF_WQT;
    const float* wkT = ws + OFF_WKT;
    const float* wvT = ws + OFF_WVT;
    const float* wfcT = ws + OFF_WFCT;

    for (int h = 0; h < 8; ++h) {
        const float* wq = wqT + h * 4096;
        const float* wk = wkT + h * 4096;
        const float* wv = wvT + h * 4096;
        // Q,K,V = feat @ W^T + b
        for (int o = t; o < 1408; o += 256) {
            int s = o >> 6, e = o & 63;
            float aq = bq[h * 64 + e], ak = bk[h * 64 + e], av = bv[h * 64 + e];
            const float* fr = f_s + s * 64;
            #pragma unroll 8
            for (int d = 0; d < 64; ++d) {
                float fv = fr[d];
                aq = fmaf(fv, wq[d * 64 + e], aq);
                ak = fmaf(fv, wk[d * 64 + e], ak);
                av = fmaf(fv, wv[d * 64 + e], av);
            }
            q_s[s * 64 + e] = aq;
            k_s[s * 65 + e] = ak;
            v_s[s * 64 + e] = av;
        }
        __syncthreads();
        // scores S = Q K^T (no 1/sqrt(d) in reference)
        for (int o = t; o < 484; o += 256) {
            int s = o / 22, u = o - s * 22;
            float acc = 0.f;
            #pragma unroll 16
            for (int e = 0; e < 64; ++e) acc = fmaf(q_s[s * 64 + e], k_s[u * 65 + e], acc);
            s_s[s * 22 + u] = acc;
        }
        __syncthreads();
        // softmax rows (22 rows, serial per thread — tiny)
        if (t < 22) {
            float m = -1e30f;
            #pragma unroll
            for (int j = 0; j < 22; ++j) m = fmaxf(m, s_s[t * 22 + j]);
            float sum = 0.f;
            #pragma unroll
            for (int j = 0; j < 22; ++j) { float ev = __expf(s_s[t * 22 + j] - m); s_s[t * 22 + j] = ev; sum += ev; }
            float r = 1.f / sum;
            #pragma unroll
            for (int j = 0; j < 22; ++j) s_s[t * 22 + j] *= r;
        }
        __syncthreads();
        // O = A V
        for (int o = t; o < 1408; o += 256) {
            int s = o >> 6, e = o & 63;
            float acc = 0.f;
            #pragma unroll
            for (int u = 0; u < 22; ++u) acc = fmaf(s_s[s * 22 + u], v_s[u * 64 + e], acc);
            o_s[s * 64 + e] = acc;
        }
        __syncthreads();
        // fc partial: fc[s][d] += O_h[s][:] @ Wfc[:, h*64: (h+1)*64]^T
        for (int o = t; o < 1408; o += 256) {
            int s = o >> 6, d = o & 63;
            float acc = (h == 0) ? bfc[d] : fc_s[o];
            const float* orow = o_s + s * 64;
            const float* wfc = wfcT + (h * 64) * 64 + d;
            #pragma unroll 8
            for (int e = 0; e < 64; ++e) acc = fmaf(orow[e], wfc[e * 64], acc);
            fc_s[o] = acc;
        }
        __syncthreads();
    }
    // mean over s, then @ Wout^T + bout
    if (t < 64) {
        float sum = 0.f;
        #pragma unroll
        for (int s = 0; s < 22; ++s) sum += fc_s[s * 64 + t];
        mean_s[t] = sum * (1.f / 22.f);
    }
    __syncthreads();
    if (t < 64) {
        const float* woutT = ws + OFF_WOUTT;
        float acc = bout[t];
        #pragma unroll 16
        for (int k = 0; k < 64; ++k) acc = fmaf(mean_s[k], woutT[k * 64 + t], acc);
        out[(size_t)b * 64 + t] = acc;
    }
}

extern "C" void kernel_launch(void* const* d_in, const int* in_sizes, int n_in,
                              void* d_out, int out_size, void* d_ws, size_t ws_size,
                              hipStream_t stream) {
    const float* audio1 = (const float*)d_in[0];
    const float* audio2 = (const float*)d_in[1];
    const float* w1   = (const float*)d_in[2];
    const float* b1   = (const float*)d_in[3];
    const float* g1   = (const float*)d_in[4];
    const float* be1  = (const float*)d_in[5];
    const float* m1   = (const float*)d_in[6];
    const float* v1   = (const float*)d_in[7];
    const float* w2   = (const float*)d_in[8];
    const float* b2   = (const float*)d_in[9];
    const float* g2   = (const float*)d_in[10];
    const float* be2  = (const float*)d_in[11];
    const float* m2   = (const float*)d_in[12];
    const float* v2   = (const float*)d_in[13];
    const float* w3   = (const float*)d_in[14];
    const float* b3   = (const float*)d_in[15];
    const float* g3   = (const float*)d_in[16];
    const float* be3  = (const float*)d_in[17];
    const float* m3   = (const float*)d_in[18];
    const float* v3   = (const float*)d_in[19];
    const float* Wq   = (const float*)d_in[20];
    const float* bq   = (const float*)d_in[21];
    const float* Wk   = (const float*)d_in[22];
    const float* bk   = (const float*)d_in[23];
    const float* Wv   = (const float*)d_in[24];
    const float* bv   = (const float*)d_in[25];
    const float* Wfc  = (const float*)d_in[26];
    const float* bfc  = (const float*)d_in[27];
    const float* Wout = (const float*)d_in[28];
    const float* bout = (const float*)d_in[29];

    float* ws  = (float*)d_ws;
    float* out = (float*)d_out;
    int B = in_sizes[0] / SEQLEN;   // 4096
    int nseq = 2 * B;               // both audios

    repack_kernel<<<524, 256, 0, stream>>>(w2, w3, Wq, Wk, Wv, Wfc, Wout, ws);
    encoder_kernel<<<nseq * 6, 256, 0, stream>>>(audio1, audio2, w1,
        b1, g1, be1, m1, v1,
        b2, g2, be2, m2, v2,
        b3, g3, be3, m3, v3,
        ws, B);
    mha_kernel<<<nseq, 256, 0, stream>>>(ws, bq, bk, bv, bfc, bout, out, B);
}

// Round 2
// 3980.783 us; speedup vs baseline: 2.5018x; 2.5018x over previous
//
#include <hip/hip_runtime.h>
#include <math.h>

#define NCHUNK 22
#define SEQLEN 600
#define BN_EPS 1e-5f

// ws float offsets
#define OFF_W2T   0          // 13312  : w2 transposed [ci][k][co]
#define OFF_W3R   13312      // 51200  : w3 transposed [j=q*32+ci][co]
#define OFF_WQT   64512      // 32768  : Wq transposed [h][d][e]
#define OFF_WKT   97280      // 32768
#define OFF_WVT   130048     // 32768
#define OFF_WFCT  162816     // 32768  : Wfc transposed [j][d]
#define OFF_WOUTT 195584     // 4096   : Wout transposed [k][d]
#define OFF_FEAT  200704     // 2*B*22*64

__device__ __forceinline__ float swishf(float z) {
    return z / (1.f + __expf(-z));
}

__global__ __launch_bounds__(256) void repack_kernel(
    const float* __restrict__ w2, const float* __restrict__ w3,
    const float* __restrict__ Wq, const float* __restrict__ Wk, const float* __restrict__ Wv,
    const float* __restrict__ Wfc, const float* __restrict__ Wout,
    float* __restrict__ ws)
{
    int tid = blockIdx.x * 256 + threadIdx.x;
    if (tid < 13312) {                       // w2t[(ci*26+k)*32+co] = w2[co][ci][k]
        int co = tid & 31, r = tid >> 5;
        int ci = r / 26, k = r - ci * 26;
        ws[OFF_W2T + tid] = w2[co * 416 + ci * 26 + k];
    }
    int t2 = tid - 13312;
    if (t2 >= 0 && t2 < 51200) {             // w3r[j*64+co] = w3[co][ci][q], j=q*32+ci
        int co = t2 & 63, j = t2 >> 6;
        int q = j >> 5, ci = j & 31;
        ws[OFF_W3R + t2] = w3[co * 800 + ci * 25 + q];
    }
    int t3 = tid - 64512;
    if (t3 >= 0 && t3 < 32768) {             // wqT[(h*64+d)*64+e] = Wq[h][e][d]
        int e = t3 & 63, hd = t3 >> 6;
        int d = hd & 63, h = hd >> 6;
        ws[OFF_WQT + t3] = Wq[h * 4096 + e * 64 + d];
        ws[OFF_WKT + t3] = Wk[h * 4096 + e * 64 + d];
        ws[OFF_WVT + t3] = Wv[h * 4096 + e * 64 + d];
    }
    int t4 = tid - 97280;
    if (t4 >= 0 && t4 < 32768) {             // wfcT[j*64+d] = Wfc[d][j]
        int d = t4 & 63, j = t4 >> 6;
        ws[OFF_WFCT + t4] = Wfc[d * 512 + j];
    }
    int t5 = tid - 130048;
    if (t5 >= 0 && t5 < 4096) {              // woutT[k*64+d] = Wout[d][k]
        int d = t5 & 63, k = t5 >> 6;
        ws[OFF_WOUTT + t5] = Wout[d * 64 + k];
    }
}

// One block = one 5-chunk tile (125 conv2 positions; tile 4 has 2 chunks / 50 q).
// conv1 -> y1t[ci][p] (transposed, rows 156). conv2: double-buffered LDS weight
// slices per ci, 4q x 4co register tile per thread, sliding y1 window in regs.
// conv3: split-K over 4 waves, weights streamed coalesced from L2.
__global__ __launch_bounds__(256, 4) void encoder_kernel(
    const float* __restrict__ audio1, const float* __restrict__ audio2,
    const float* __restrict__ w1,
    const float* __restrict__ b1, const float* __restrict__ g1, const float* __restrict__ be1,
    const float* __restrict__ m1, const float* __restrict__ v1,
    const float* __restrict__ b2, const float* __restrict__ g2, const float* __restrict__ be2,
    const float* __restrict__ m2, const float* __restrict__ v2,
    const float* __restrict__ b3, const float* __restrict__ g3, const float* __restrict__ be3,
    const float* __restrict__ m3, const float* __restrict__ v3,
    float* __restrict__ ws, int B)
{
    __shared__ float smem[8976];
    float* a_s   = smem;            // 176
    float* w1_s  = smem + 176;      // 416
    float* A_s   = smem + 592;      // 112  (folded BN scale)
    float* Bc_s  = smem + 704;      // 112  (folded BN shift)
    float* w2s   = smem + 816;      // 2 x 832 double-buffered conv2 weight slice [k][co]
    float* y1t   = smem + 2480;     // 16 x 156, [ci][p]
    float* red_s = smem + 2480;     // 4*5*64 = 1280, ALIAS over y1t (dead after conv2)
    float* y2_s  = smem + 4976;     // 4000, [q][32]

    int t = threadIdx.x;
    int blk = blockIdx.x;
    int seq = blk / 5, tile = blk - seq * 5;
    int tc = (tile == 4) ? 2 : 5;           // chunks in this tile
    int nq = 25 * tc;                       // conv2 output positions
    int ny1 = nq + 25;                      // conv1 positions needed
    int na = nq + 50;                       // audio samples needed

    const float* audio = (seq < B ? audio1 + (size_t)seq * SEQLEN
                                  : audio2 + (size_t)(seq - B) * SEQLEN) + tile * 125;
    if (t < na) a_s[t] = audio[t];
    for (int i = t; i < 416; i += 256) w1_s[i] = w1[i];
    if (t < 16)       { float A = g1[t] * rsqrtf(v1[t] + BN_EPS); A_s[t] = A; Bc_s[t] = (b1[t] - m1[t]) * A + be1[t]; }
    else if (t < 48)  { int i = t - 16; float A = g2[i] * rsqrtf(v2[i] + BN_EPS); A_s[t] = A; Bc_s[t] = (b2[i] - m2[i]) * A + be2[i]; }
    else if (t < 112) { int i = t - 48; float A = g3[i] * rsqrtf(v3[i] + BN_EPS); A_s[t] = A; Bc_s[t] = (b3[i] - m3[i]) * A + be3[i]; }
    // stage conv2 weight slice ci=0
    for (int i = t; i < 832; i += 256) w2s[i] = ws[OFF_W2T + i];
    __syncthreads();

    // ---- conv1 + bn + swish -> y1t[ci][p] ----
    for (int o = t; o < ny1 * 16; o += 256) {
        int p = o >> 4, ci = o & 15;
        float acc = 0.f;
        #pragma unroll
        for (int k = 0; k < 26; ++k) acc = fmaf(a_s[p + k], w1_s[ci * 26 + k], acc);
        y1t[ci * 156 + p] = swishf(fmaf(acc, A_s[ci], Bc_s[ci]));
    }
    // (barrier at top of ci-loop below covers the y1t dependency)

    // ---- conv2: acc[qi][cj], loop ci with double-buffered weights ----
    int cg = t & 7, qg = t >> 3;            // co group (4), q group (4)
    int q0 = qg * 4;
    float acc00=0.f,acc01=0.f,acc02=0.f,acc03=0.f;
    float acc10=0.f,acc11=0.f,acc12=0.f,acc13=0.f;
    float acc20=0.f,acc21=0.f,acc22=0.f,acc23=0.f;
    float acc30=0.f,acc31=0.f,acc32=0.f,acc33=0.f;

    for (int ci = 0; ci < 16; ++ci) {
        __syncthreads();
        if (ci < 15) {                      // prefetch next slice into the other buffer
            const float* src = ws + OFF_W2T + (ci + 1) * 832;
            float* dst = w2s + ((ci + 1) & 1) * 832;
            for (int i = t; i < 832; i += 256) dst[i] = src[i];
        }
        const float4* wbuf = (const float4*)(w2s + (ci & 1) * 832);  // [k*8+cg]
        const float* yrow = y1t + ci * 156;
        float4 win = *(const float4*)(yrow + q0);
        float yv0 = win.x, yv1 = win.y, yv2 = win.z, yv3 = win.w;
        #pragma unroll
        for (int k = 0; k < 26; ++k) {
            float4 wg = wbuf[k * 8 + cg];
            acc00 = fmaf(yv0, wg.x, acc00); acc01 = fmaf(yv0, wg.y, acc01);
            acc02 = fmaf(yv0, wg.z, acc02); acc03 = fmaf(yv0, wg.w, acc03);
            acc10 = fmaf(yv1, wg.x, acc10); acc11 = fmaf(yv1, wg.y, acc11);
            acc12 = fmaf(yv1, wg.z, acc12); acc13 = fmaf(yv1, wg.w, acc13);
            acc20 = fmaf(yv2, wg.x, acc20); acc21 = fmaf(yv2, wg.y, acc21);
            acc22 = fmaf(yv2, wg.z, acc22); acc23 = fmaf(yv2, wg.w, acc23);
            acc30 = fmaf(yv3, wg.x, acc30); acc31 = fmaf(yv3, wg.y, acc31);
            acc32 = fmaf(yv3, wg.z, acc32); acc33 = fmaf(yv3, wg.w, acc33);
            yv0 = yv1; yv1 = yv2; yv2 = yv3;
            if (k < 25) yv3 = yrow[q0 + k + 4];
        }
    }
    // bn + swish + store y2
    {
        int co0 = 16 + cg * 4;
        float A0 = A_s[co0], A1 = A_s[co0+1], A2 = A_s[co0+2], A3 = A_s[co0+3];
        float B0 = Bc_s[co0], B1 = Bc_s[co0+1], B2 = Bc_s[co0+2], B3 = Bc_s[co0+3];
        float4 r;
        if (q0 + 0 < nq) { r.x = swishf(fmaf(acc00,A0,B0)); r.y = swishf(fmaf(acc01,A1,B1));
                           r.z = swishf(fmaf(acc02,A2,B2)); r.w = swishf(fmaf(acc03,A3,B3));
                           *(float4*)(y2_s + (q0+0)*32 + cg*4) = r; }
        if (q0 + 1 < nq) { r.x = swishf(fmaf(acc10,A0,B0)); r.y = swishf(fmaf(acc11,A1,B1));
                           r.z = swishf(fmaf(acc12,A2,B2)); r.w = swishf(fmaf(acc13,A3,B3));
                           *(float4*)(y2_s + (q0+1)*32 + cg*4) = r; }
        if (q0 + 2 < nq) { r.x = swishf(fmaf(acc20,A0,B0)); r.y = swishf(fmaf(acc21,A1,B1));
                           r.z = swishf(fmaf(acc22,A2,B2)); r.w = swishf(fmaf(acc23,A3,B3));
                           *(float4*)(y2_s + (q0+2)*32 + cg*4) = r; }
        if (q0 + 3 < nq) { r.x = swishf(fmaf(acc30,A0,B0)); r.y = swishf(fmaf(acc31,A1,B1));
                           r.z = swishf(fmaf(acc32,A2,B2)); r.w = swishf(fmaf(acc33,A3,B3));
                           *(float4*)(y2_s + (q0+3)*32 + cg*4) = r; }
    }
    __syncthreads();

    // ---- conv3 split-K: wave `part` handles j in [part*200, part*200+200) ----
    {
        const float* wp = ws + OFF_W3R + (size_t)((t >> 6) * 200) * 64 + (t & 63);
        int jb = (t >> 6) * 200;
        float c0=0.f,c1=0.f,c2=0.f,c3=0.f,c4=0.f;
        for (int i = 0; i < 200; i += 4) {
            float w0 = wp[(i + 0) * 64];
            float wa = wp[(i + 1) * 64];
            float wb = wp[(i + 2) * 64];
            float wc = wp[(i + 3) * 64];
            float4 ya = *(const float4*)(y2_s + 0 * 800 + jb + i);
            float4 yb = *(const float4*)(y2_s + 1 * 800 + jb + i);
            float4 yc = *(const float4*)(y2_s + 2 * 800 + jb + i);
            float4 yd = *(const float4*)(y2_s + 3 * 800 + jb + i);
            float4 ye = *(const float4*)(y2_s + 4 * 800 + jb + i);
            c0 = fmaf(ya.x, w0, fmaf(ya.y, wa, fmaf(ya.z, wb, fmaf(ya.w, wc, c0))));
            c1 = fmaf(yb.x, w0, fmaf(yb.y, wa, fmaf(yb.z, wb, fmaf(yb.w, wc, c1))));
            c2 = fmaf(yc.x, w0, fmaf(yc.y, wa, fmaf(yc.z, wb, fmaf(yc.w, wc, c2))));
            c3 = fmaf(yd.x, w0, fmaf(yd.y, wa, fmaf(yd.z, wb, fmaf(yd.w, wc, c3))));
            c4 = fmaf(ye.x, w0, fmaf(ye.y, wa, fmaf(ye.z, wb, fmaf(ye.w, wc, c4))));
        }
        int part = t >> 6, co = t & 63;
        red_s[(part * 5 + 0) * 64 + co] = c0;
        red_s[(part * 5 + 1) * 64 + co] = c1;
        red_s[(part * 5 + 2) * 64 + co] = c2;
        red_s[(part * 5 + 3) * 64 + co] = c3;
        red_s[(part * 5 + 4) * 64 + co] = c4;
    }
    __syncthreads();
    for (int i = t; i < tc * 64; i += 256) {
        int cc = i >> 6, co = i & 63;
        float s = red_s[(0 * 5 + cc) * 64 + co] + red_s[(1 * 5 + cc) * 64 + co]
                + red_s[(2 * 5 + cc) * 64 + co] + red_s[(3 * 5 + cc) * 64 + co];
        ws[OFF_FEAT + ((size_t)(seq * NCHUNK + tile * 5 + cc)) * 64 + co]
            = swishf(fmaf(s, A_s[48 + co], Bc_s[48 + co]));
    }
}

// One block per sequence. QKV and fc register-tile 6 sequence rows per thread
// (18 / 6 FMA chains per weight load) to hide L2 latency.
__global__ __launch_bounds__(256, 4) void mha_kernel(
    const float* __restrict__ ws,
    const float* __restrict__ bq, const float* __restrict__ bk, const float* __restrict__ bv,
    const float* __restrict__ bfc, const float* __restrict__ bout,
    float* __restrict__ out, int B)
{
    __shared__ float f_s[22 * 64];
    __shared__ float q_s[22 * 64];
    __shared__ float k_s[22 * 65];   // pad 65: break stride-64 in QK^T
    __shared__ float v_s[22 * 64];
    __shared__ float s_s[22 * 22];
    __shared__ float o_s[22 * 64];
    __shared__ float fc_s[22 * 64];
    __shared__ float mean_s[64];

    int t = threadIdx.x;
    int b = blockIdx.x;
    const float* feat = ws + OFF_FEAT + (size_t)b * 22 * 64;
    for (int i = t; i < 1408; i += 256) f_s[i] = feat[i];
    __syncthreads();

    int e = t & 63, sg = t >> 6;            // sg uniform per wave
    int ns = (sg < 2) ? 6 : 5;              // rows s = sg, sg+4, ...

    for (int h = 0; h < 8; ++h) {
        const float* wq = ws + OFF_WQT + h * 4096;
        const float* wk = ws + OFF_WKT + h * 4096;
        const float* wv = ws + OFF_WVT + h * 4096;
        // Q,K,V = feat @ W^T + b : 6 rows per thread
        {
            float aq[6], ak[6], av[6];
            float bqv = bq[h * 64 + e], bkv = bk[h * 64 + e], bvv = bv[h * 64 + e];
            #pragma unroll
            for (int i = 0; i < 6; ++i) { aq[i] = bqv; ak[i] = bkv; av[i] = bvv; }
            #pragma unroll 2
            for (int d = 0; d < 64; ++d) {
                float wqv = wq[d * 64 + e];
                float wkv = wk[d * 64 + e];
                float wvv = wv[d * 64 + e];
                #pragma unroll
                for (int i = 0; i < 6; ++i) {
                    if (i < ns) {
                        float fv = f_s[(sg + 4 * i) * 64 + d];
                        aq[i] = fmaf(fv, wqv, aq[i]);
                        ak[i] = fmaf(fv, wkv, ak[i]);
                        av[i] = fmaf(fv, wvv, av[i]);
                    }
                }
            }
            #pragma unroll
            for (int i = 0; i < 6; ++i) {
                if (i < ns) {
                    int s = sg + 4 * i;
                    q_s[s * 64 + e] = aq[i];
                    k_s[s * 65 + e] = ak[i];
                    v_s[s * 64 + e] = av[i];
                }
            }
        }
        __syncthreads();
        // scores S = Q K^T (no 1/sqrt(d) in reference)
        for (int o = t; o < 484; o += 256) {
            int s = o / 22, u = o - s * 22;
            float acc = 0.f;
            #pragma unroll 16
            for (int d = 0; d < 64; ++d) acc = fmaf(q_s[s * 64 + d], k_s[u * 65 + d], acc);
            s_s[s * 22 + u] = acc;
        }
        __syncthreads();
        // softmax rows
        if (t < 22) {
            float m = -1e30f;
            #pragma unroll
            for (int j = 0; j < 22; ++j) m = fmaxf(m, s_s[t * 22 + j]);
            float sum = 0.f;
            #pragma unroll
            for (int j = 0; j < 22; ++j) { float ev = __expf(s_s[t * 22 + j] - m); s_s[t * 22 + j] = ev; sum += ev; }
            float r = 1.f / sum;
            #pragma unroll
            for (int j = 0; j < 22; ++j) s_s[t * 22 + j] *= r;
        }
        __syncthreads();
        // O = A V
        for (int o = t; o < 1408; o += 256) {
            int s = o >> 6, ee = o & 63;
            float acc = 0.f;
            #pragma unroll
            for (int u = 0; u < 22; ++u) acc = fmaf(s_s[s * 22 + u], v_s[u * 64 + ee], acc);
            o_s[s * 64 + ee] = acc;
        }
        __syncthreads();
        // fc partial: fc[s][d] += O_h[s][:] @ Wfc[:, h*64:(h+1)*64]^T, 6 rows/thread
        {
            int d = e;                       // reuse lane mapping
            float afc[6];
            #pragma unroll
            for (int i = 0; i < 6; ++i) {
                if (i < ns) afc[i] = (h == 0) ? bfc[d] : fc_s[(sg + 4 * i) * 64 + d];
            }
            const float* wfc = ws + OFF_WFCT + (size_t)(h * 64) * 64 + d;
            #pragma unroll 2
            for (int e2 = 0; e2 < 64; ++e2) {
                float wvv = wfc[e2 * 64];
                #pragma unroll
                for (int i = 0; i < 6; ++i) {
                    if (i < ns) afc[i] = fmaf(o_s[(sg + 4 * i) * 64 + e2], wvv, afc[i]);
                }
            }
            __syncthreads();                 // o_s/fc_s read-write ordering across heads
            #pragma unroll
            for (int i = 0; i < 6; ++i) {
                if (i < ns) fc_s[(sg + 4 * i) * 64 + d] = afc[i];
            }
        }
        __syncthreads();
    }
    // mean over s, then @ Wout^T + bout
    if (t < 64) {
        float sum = 0.f;
        #pragma unroll
        for (int s = 0; s < 22; ++s) sum += fc_s[s * 64 + t];
        mean_s[t] = sum * (1.f / 22.f);
    }
    __syncthreads();
    if (t < 64) {
        const float* woutT = ws + OFF_WOUTT;
        float acc = bout[t];
        #pragma unroll 16
        for (int k = 0; k < 64; ++k) acc = fmaf(mean_s[k], woutT[k * 64 + t], acc);
        out[(size_t)b * 64 + t] = acc;
    }
}

extern "C" void kernel_launch(void* const* d_in, const int* in_sizes, int n_in,
                              void* d_out, int out_size, void* d_ws, size_t ws_size,
                              hipStream_t stream) {
    const float* audio1 = (const float*)d_in[0];
    const float* audio2 = (const float*)d_in[1];
    const float* w1   = (const float*)d_in[2];
    const float* b1   = (const float*)d_in[3];
    const float* g1   = (const float*)d_in[4];
    const float* be1  = (const float*)d_in[5];
    const float* m1   = (const float*)d_in[6];
    const float* v1   = (const float*)d_in[7];
    const float* w2   = (const float*)d_in[8];
    const float* b2   = (const float*)d_in[9];
    const float* g2   = (const float*)d_in[10];
    const float* be2  = (const float*)d_in[11];
    const float* m2   = (const float*)d_in[12];
    const float* v2   = (const float*)d_in[13];
    const float* w3   = (const float*)d_in[14];
    const float* b3   = (const float*)d_in[15];
    const float* g3   = (const float*)d_in[16];
    const float* be3  = (const float*)d_in[17];
    const float* m3   = (const float*)d_in[18];
    const float* v3   = (const float*)d_in[19];
    const float* Wq   = (const float*)d_in[20];
    const float* bq   = (const float*)d_in[21];
    const float* Wk   = (const float*)d_in[22];
    const float* bk   = (const float*)d_in[23];
    const float* Wv   = (const float*)d_in[24];
    const float* bv   = (const float*)d_in[25];
    const float* Wfc  = (const float*)d_in[26];
    const float* bfc  = (const float*)d_in[27];
    const float* Wout = (const float*)d_in[28];
    const float* bout = (const float*)d_in[29];

    float* ws  = (float*)d_ws;
    float* out = (float*)d_out;
    int B = in_sizes[0] / SEQLEN;   // 4096
    int nseq = 2 * B;

    repack_kernel<<<524, 256, 0, stream>>>(w2, w3, Wq, Wk, Wv, Wfc, Wout, ws);
    encoder_kernel<<<nseq * 5, 256, 0, stream>>>(audio1, audio2, w1,
        b1, g1, be1, m1, v1,
        b2, g2, be2, m2, v2,
        b3, g3, be3, m3, v3,
        ws, B);
    mha_kernel<<<nseq, 256, 0, stream>>>(ws, bq, bk, bv, bfc, bout, out, B);
}

// Round 3
// 2159.380 us; speedup vs baseline: 4.6120x; 1.8435x over previous
//
#include <hip/hip_runtime.h>
#include <math.h>

#define NCHUNK 22
#define SEQLEN 600
#define BN_EPS 1e-5f
#define Y1S 164              // y1t row stride (164%32=4 -> conflict-free writes)

// ws offsets (4-byte units)
#define OFF_W2F   0          // 16384 u32 : w2 MFMA B-frags [s][n][hl][lane][reg] (bf16 pairs)
#define OFF_W3R   16384      // 51200 f32 : w3 transposed [j=q*32+ci][co]
#define OFF_WQT   67584      // 32768
#define OFF_WKT   100352     // 32768
#define OFF_WVT   133120     // 32768
#define OFF_WFCT  165888     // 32768 : Wfc transposed [j][d]
#define OFF_WOUTT 198656     // 4096  : Wout transposed [k][d]
#define OFF_FEAT  202752     // 2*B*22*64

typedef short bf16x8 __attribute__((ext_vector_type(8)));
typedef float f32x4 __attribute__((ext_vector_type(4)));

__device__ __forceinline__ float swishf(float z) {
    return z / (1.f + __expf(-z));
}
__device__ __forceinline__ unsigned short bf16_rne(float f) {
    unsigned int u = __float_as_uint(f);
    return (unsigned short)((u + 0x7FFFu + ((u >> 16) & 1u)) >> 16);
}
__device__ __forceinline__ float bf16_tof(unsigned short h) {
    return __uint_as_float(((unsigned int)h) << 16);
}

__global__ __launch_bounds__(256) void repack_kernel(
    const float* __restrict__ w2, const float* __restrict__ w3,
    const float* __restrict__ Wq, const float* __restrict__ Wk, const float* __restrict__ Wv,
    const float* __restrict__ Wfc, const float* __restrict__ Wout,
    float* __restrict__ ws)
{
    int tid = blockIdx.x * 256 + threadIdx.x;
    unsigned int* wsu = (unsigned int*)ws;
    if (tid < 16384) {                       // w2 B-frags, K padded 416->512 (k>=26 zero)
        int r = tid & 3, l = (tid >> 2) & 63, hl = (tid >> 8) & 1;
        int n = (tid >> 9) & 1, s = tid >> 10;
        int co = n * 16 + (l & 15);
        int k0 = 8 * (l >> 4) + 2 * r;
        float f0 = (k0     < 26) ? w2[co * 416 + s * 26 + k0]     : 0.f;
        float f1 = (k0 + 1 < 26) ? w2[co * 416 + s * 26 + k0 + 1] : 0.f;
        unsigned short h0 = bf16_rne(f0), h1 = bf16_rne(f1);
        unsigned int val;
        if (hl == 0) val = (unsigned int)h0 | ((unsigned int)h1 << 16);
        else {
            unsigned short l0 = bf16_rne(f0 - bf16_tof(h0));
            unsigned short l1 = bf16_rne(f1 - bf16_tof(h1));
            val = (unsigned int)l0 | ((unsigned int)l1 << 16);
        }
        wsu[OFF_W2F + tid] = val;
    }
    int t2 = tid - 16384;
    if (t2 >= 0 && t2 < 51200) {             // w3r[j*64+co] = w3[co][ci][q], j=q*32+ci
        int co = t2 & 63, j = t2 >> 6;
        int q = j >> 5, ci = j & 31;
        ws[OFF_W3R + t2] = w3[co * 800 + ci * 25 + q];
    }
    int t3 = tid - 67584;
    if (t3 >= 0 && t3 < 32768) {             // wqT[(h*64+d)*64+e] = Wq[h][e][d]
        int e = t3 & 63, hd = t3 >> 6;
        int d = hd & 63, h = hd >> 6;
        ws[OFF_WQT + t3] = Wq[h * 4096 + e * 64 + d];
        ws[OFF_WKT + t3] = Wk[h * 4096 + e * 64 + d];
        ws[OFF_WVT + t3] = Wv[h * 4096 + e * 64 + d];
    }
    int t4 = tid - 100352;
    if (t4 >= 0 && t4 < 32768) {             // wfcT[j*64+d] = Wfc[d][j]
        int d = t4 & 63, j = t4 >> 6;
        ws[OFF_WFCT + t4] = Wfc[d * 512 + j];
    }
    int t5 = tid - 133120;
    if (t5 >= 0 && t5 < 4096) {              // woutT[k*64+d] = Wout[d][k]
        int d = t5 & 63, k = t5 >> 6;
        ws[OFF_WOUTT + t5] = Wout[d * 64 + k];
    }
}

// One block = one 5-chunk tile. conv1 fp32 -> y1t[ci][p]; conv2 = bf16x3 MFMA
// (16x16x32, K padded to 512, 2 Mtiles x 2 Ntiles per wave, B-frags pre-swizzled
// in ws and double-buffered through LDS); conv3 fp32 split-K over 4 waves.
__global__ __launch_bounds__(256, 4) void encoder_kernel(
    const float* __restrict__ audio1, const float* __restrict__ audio2,
    const float* __restrict__ w1,
    const float* __restrict__ b1, const float* __restrict__ g1, const float* __restrict__ be1,
    const float* __restrict__ m1, const float* __restrict__ v1,
    const float* __restrict__ b2, const float* __restrict__ g2, const float* __restrict__ be2,
    const float* __restrict__ m2, const float* __restrict__ v2,
    const float* __restrict__ b3, const float* __restrict__ g3, const float* __restrict__ be3,
    const float* __restrict__ m3, const float* __restrict__ v3,
    float* __restrict__ ws, int B)
{
    __shared__ float smem[9488];
    float* a_s   = smem;                    // 176
    float* w1_s  = smem + 176;              // 416
    float* A_s   = smem + 592;              // 112
    float* Bc_s  = smem + 704;              // 112
    unsigned int* w2f = (unsigned int*)(smem + 816);   // 2 x 1024 u32 dbuf
    float* y1t   = smem + 2864;             // 16 x 164
    float* red_s = smem + 2864;             // 1280, alias (dead after conv2)
    float* y2_s  = smem + 5488;             // 4000 [q][32]

    int t = threadIdx.x;
    int blk = blockIdx.x;
    int seq = blk / 5, tile = blk - seq * 5;
    int tc = (tile == 4) ? 2 : 5;
    int nq = 25 * tc;                       // 125 or 50
    int ny1 = nq + 25;
    int na = nq + 50;
    const unsigned int* wsu = (const unsigned int*)ws;

    const float* audio = (seq < B ? audio1 + (size_t)seq * SEQLEN
                                  : audio2 + (size_t)(seq - B) * SEQLEN) + tile * 125;
    if (t < na) a_s[t] = audio[t];
    for (int i = t; i < 416; i += 256) w1_s[i] = w1[i];
    if (t < 16)       { float A = g1[t] * rsqrtf(v1[t] + BN_EPS); A_s[t] = A; Bc_s[t] = (b1[t] - m1[t]) * A + be1[t]; }
    else if (t < 48)  { int i = t - 16; float A = g2[i] * rsqrtf(v2[i] + BN_EPS); A_s[t] = A; Bc_s[t] = (b2[i] - m2[i]) * A + be2[i]; }
    else if (t < 112) { int i = t - 48; float A = g3[i] * rsqrtf(v3[i] + BN_EPS); A_s[t] = A; Bc_s[t] = (b3[i] - m3[i]) * A + be3[i]; }
    {   // stage B-frag step 0 into buf0
        uint4 v = *(const uint4*)(wsu + OFF_W2F + t * 4);
        *(uint4*)(w2f + t * 4) = v;
    }
    __syncthreads();

    // ---- conv1 + bn + swish -> y1t[ci][p] ----
    for (int o = t; o < ny1 * 16; o += 256) {
        int p = o >> 4, ci = o & 15;
        float acc = 0.f;
        #pragma unroll
        for (int k = 0; k < 26; ++k) acc = fmaf(a_s[p + k], w1_s[ci * 26 + k], acc);
        y1t[ci * Y1S + p] = swishf(fmaf(acc, A_s[ci], Bc_s[ci]));
    }
    // zero tail so padded-k gathers can't read NaN garbage
    for (int i = t; i < 16 * 40; i += 256) {
        int ci = i / 40, j = i - (i / 40) * 40;
        int p = ny1 + j;
        if (p < Y1S) y1t[ci * Y1S + p] = 0.f;
    }

    // ---- conv2 MFMA: C[q][co], 16 K-steps (ci), bf16x3 ----
    int lane = t & 63, wid = t >> 6;
    int li = lane & 15, lg = lane >> 4;
    int nmt = (nq + 15) >> 4;               // 8 or 4
    f32x4 acc00 = {0.f,0.f,0.f,0.f}, acc01 = acc00, acc10 = acc00, acc11 = acc00;
    int mt0 = wid, mt1 = wid + 4;
    int base0 = mt0 * 16 + li + lg * 8;
    int base1 = mt1 * 16 + li + lg * 8;

    for (int s = 0; s < 16; ++s) {
        __syncthreads();
        if (s < 15) {
            uint4 v = *(const uint4*)(wsu + OFF_W2F + (s + 1) * 1024 + t * 4);
            *(uint4*)(w2f + ((s + 1) & 1) * 1024 + t * 4) = v;
        }
        const unsigned int* cur = w2f + (s & 1) * 1024;
        bf16x8 bh0 = *(const bf16x8*)(cur + lane * 4);
        bf16x8 bl0 = *(const bf16x8*)(cur + 256 + lane * 4);
        bf16x8 bh1 = *(const bf16x8*)(cur + 512 + lane * 4);
        bf16x8 bl1 = *(const bf16x8*)(cur + 768 + lane * 4);
        const float* yrow = y1t + s * Y1S;
        {   // Mtile 0
            bf16x8 ah, al;
            #pragma unroll
            for (int e = 0; e < 8; ++e) {
                float f = yrow[base0 + e];
                unsigned short h = bf16_rne(f);
                ah[e] = (short)h;
                al[e] = (short)bf16_rne(f - bf16_tof(h));
            }
            acc00 = __builtin_amdgcn_mfma_f32_16x16x32_bf16(ah, bh0, acc00, 0, 0, 0);
            acc00 = __builtin_amdgcn_mfma_f32_16x16x32_bf16(al, bh0, acc00, 0, 0, 0);
            acc00 = __builtin_amdgcn_mfma_f32_16x16x32_bf16(ah, bl0, acc00, 0, 0, 0);
            acc01 = __builtin_amdgcn_mfma_f32_16x16x32_bf16(ah, bh1, acc01, 0, 0, 0);
            acc01 = __builtin_amdgcn_mfma_f32_16x16x32_bf16(al, bh1, acc01, 0, 0, 0);
            acc01 = __builtin_amdgcn_mfma_f32_16x16x32_bf16(ah, bl1, acc01, 0, 0, 0);
        }
        if (nmt == 8) {   // Mtile 1 (wave-uniform branch)
            bf16x8 ah, al;
            #pragma unroll
            for (int e = 0; e < 8; ++e) {
                float f = yrow[base1 + e];
                unsigned short h = bf16_rne(f);
                ah[e] = (short)h;
                al[e] = (short)bf16_rne(f - bf16_tof(h));
            }
            acc10 = __builtin_amdgcn_mfma_f32_16x16x32_bf16(ah, bh0, acc10, 0, 0, 0);
            acc10 = __builtin_amdgcn_mfma_f32_16x16x32_bf16(al, bh0, acc10, 0, 0, 0);
            acc10 = __builtin_amdgcn_mfma_f32_16x16x32_bf16(ah, bl0, acc10, 0, 0, 0);
            acc11 = __builtin_amdgcn_mfma_f32_16x16x32_bf16(ah, bh1, acc11, 0, 0, 0);
            acc11 = __builtin_amdgcn_mfma_f32_16x16x32_bf16(al, bh1, acc11, 0, 0, 0);
            acc11 = __builtin_amdgcn_mfma_f32_16x16x32_bf16(ah, bl1, acc11, 0, 0, 0);
        }
    }
    // epilogue: bn + swish -> y2_s[q][co]; D row = lg*4+r, col = li
    {
        int co0 = 16 + li, co1 = 16 + 16 + li;
        float A0 = A_s[co0], B0 = Bc_s[co0];
        float A1 = A_s[co1], B1 = Bc_s[co1];
        #pragma unroll
        for (int r = 0; r < 4; ++r) {
            int q = mt0 * 16 + lg * 4 + r;
            if (q < nq) {
                y2_s[q * 32 + li]      = swishf(fmaf(acc00[r], A0, B0));
                y2_s[q * 32 + 16 + li] = swishf(fmaf(acc01[r], A1, B1));
            }
        }
        if (nmt == 8) {
            #pragma unroll
            for (int r = 0; r < 4; ++r) {
                int q = mt1 * 16 + lg * 4 + r;
                if (q < nq) {
                    y2_s[q * 32 + li]      = swishf(fmaf(acc10[r], A0, B0));
                    y2_s[q * 32 + 16 + li] = swishf(fmaf(acc11[r], A1, B1));
                }
            }
        }
    }
    __syncthreads();

    // ---- conv3 split-K over 4 waves (fp32) ----
    {
        const float* wp = ws + OFF_W3R + (size_t)((t >> 6) * 200) * 64 + (t & 63);
        int jb = (t >> 6) * 200;
        float c0=0.f,c1=0.f,c2=0.f,c3=0.f,c4=0.f;
        for (int i = 0; i < 200; i += 4) {
            float w0 = wp[(i + 0) * 64];
            float wa = wp[(i + 1) * 64];
            float wb = wp[(i + 2) * 64];
            float wc = wp[(i + 3) * 64];
            float4 ya = *(const float4*)(y2_s + 0 * 800 + jb + i);
            float4 yb = *(const float4*)(y2_s + 1 * 800 + jb + i);
            float4 yc = *(const float4*)(y2_s + 2 * 800 + jb + i);
            float4 yd = *(const float4*)(y2_s + 3 * 800 + jb + i);
            float4 ye = *(const float4*)(y2_s + 4 * 800 + jb + i);
            c0 = fmaf(ya.x, w0, fmaf(ya.y, wa, fmaf(ya.z, wb, fmaf(ya.w, wc, c0))));
            c1 = fmaf(yb.x, w0, fmaf(yb.y, wa, fmaf(yb.z, wb, fmaf(yb.w, wc, c1))));
            c2 = fmaf(yc.x, w0, fmaf(yc.y, wa, fmaf(yc.z, wb, fmaf(yc.w, wc, c2))));
            c3 = fmaf(yd.x, w0, fmaf(yd.y, wa, fmaf(yd.z, wb, fmaf(yd.w, wc, c3))));
            c4 = fmaf(ye.x, w0, fmaf(ye.y, wa, fmaf(ye.z, wb, fmaf(ye.w, wc, c4))));
        }
        __syncthreads();                     // all y1t reads done before red_s alias write
        int part = t >> 6, co = t & 63;
        red_s[(part * 5 + 0) * 64 + co] = c0;
        red_s[(part * 5 + 1) * 64 + co] = c1;
        red_s[(part * 5 + 2) * 64 + co] = c2;
        red_s[(part * 5 + 3) * 64 + co] = c3;
        red_s[(part * 5 + 4) * 64 + co] = c4;
    }
    __syncthreads();
    for (int i = t; i < tc * 64; i += 256) {
        int cc = i >> 6, co = i & 63;
        float s = red_s[(0 * 5 + cc) * 64 + co] + red_s[(1 * 5 + cc) * 64 + co]
                + red_s[(2 * 5 + cc) * 64 + co] + red_s[(3 * 5 + cc) * 64 + co];
        ws[OFF_FEAT + ((size_t)(seq * NCHUNK + tile * 5 + cc)) * 64 + co]
            = swishf(fmaf(s, A_s[48 + co], Bc_s[48 + co]));
    }
}

// One block per sequence. mean folded: mean_s(O) = (col-mean of A) @ V, and fc
// applied once to the pooled 512-vector instead of per-row.
__global__ __launch_bounds__(256, 4) void mha_kernel(
    const float* __restrict__ ws,
    const float* __restrict__ bq, const float* __restrict__ bk, const float* __restrict__ bv,
    const float* __restrict__ bfc, const float* __restrict__ bout,
    float* __restrict__ out, int B)
{
    __shared__ float f_s[22 * 64];
    __shared__ float q_s[22 * 64];
    __shared__ float k_s[22 * 65];
    __shared__ float v_s[22 * 64];
    __shared__ float s_s[22 * 22];
    __shared__ float abar_s[22];
    __shared__ float obar_s[8 * 64];
    __shared__ float fred[4][64];
    __shared__ float fcbar_s[64];

    int t = threadIdx.x;
    int b = blockIdx.x;
    const float* feat = ws + OFF_FEAT + (size_t)b * 22 * 64;
    for (int i = t; i < 1408; i += 256) f_s[i] = feat[i];
    __syncthreads();

    int e = t & 63, sg = t >> 6;
    int ns = (sg < 2) ? 6 : 5;

    for (int h = 0; h < 8; ++h) {
        const float* wq = ws + OFF_WQT + h * 4096;
        const float* wk = ws + OFF_WKT + h * 4096;
        const float* wv = ws + OFF_WVT + h * 4096;
        {
            float aq[6], ak[6], av[6];
            float bqv = bq[h * 64 + e], bkv = bk[h * 64 + e], bvv = bv[h * 64 + e];
            #pragma unroll
            for (int i = 0; i < 6; ++i) { aq[i] = bqv; ak[i] = bkv; av[i] = bvv; }
            #pragma unroll 2
            for (int d = 0; d < 64; ++d) {
                float wqv = wq[d * 64 + e];
                float wkv = wk[d * 64 + e];
                float wvv = wv[d * 64 + e];
                #pragma unroll
                for (int i = 0; i < 6; ++i) {
                    if (i < ns) {
                        float fv = f_s[(sg + 4 * i) * 64 + d];
                        aq[i] = fmaf(fv, wqv, aq[i]);
                        ak[i] = fmaf(fv, wkv, ak[i]);
                        av[i] = fmaf(fv, wvv, av[i]);
                    }
                }
            }
            #pragma unroll
            for (int i = 0; i < 6; ++i) {
                if (i < ns) {
                    int s = sg + 4 * i;
                    q_s[s * 64 + e] = aq[i];
                    k_s[s * 65 + e] = ak[i];
                    v_s[s * 64 + e] = av[i];
                }
            }
        }
        __syncthreads();
        for (int o = t; o < 484; o += 256) {
            int s = o / 22, u = o - s * 22;
            float acc = 0.f;
            #pragma unroll 16
            for (int d = 0; d < 64; ++d) acc = fmaf(q_s[s * 64 + d], k_s[u * 65 + d], acc);
            s_s[s * 22 + u] = acc;
        }
        __syncthreads();
        if (t < 22) {
            float m = -1e30f;
            #pragma unroll
            for (int j = 0; j < 22; ++j) m = fmaxf(m, s_s[t * 22 + j]);
            float sum = 0.f;
            #pragma unroll
            for (int j = 0; j < 22; ++j) { float ev = __expf(s_s[t * 22 + j] - m); s_s[t * 22 + j] = ev; sum += ev; }
            float r = 1.f / sum;
            #pragma unroll
            for (int j = 0; j < 22; ++j) s_s[t * 22 + j] *= r;
        }
        __syncthreads();
        if (t < 22) {   // column means of A
            float a = 0.f;
            #pragma unroll
            for (int s = 0; s < 22; ++s) a += s_s[s * 22 + t];
            abar_s[t] = a * (1.f / 22.f);
        }
        __syncthreads();
        if (t < 64) {   // pooled O for this head
            float acc = 0.f;
            #pragma unroll
            for (int u = 0; u < 22; ++u) acc = fmaf(abar_s[u], v_s[u * 64 + t], acc);
            obar_s[h * 64 + t] = acc;
        }
        __syncthreads();
    }
    // fcbar = obar(512) @ WfcT + bfc, split over 4 wave-parts
    {
        int d = t & 63, part = t >> 6;
        const float* wfc = ws + OFF_WFCT + d;
        float acc = 0.f;
        for (int j = part * 128; j < part * 128 + 128; ++j)
            acc = fmaf(obar_s[j], wfc[j * 64], acc);
        fred[part][d] = acc;
    }
    __syncthreads();
    if (t < 64) fcbar_s[t] = bfc[t] + fred[0][t] + fred[1][t] + fred[2][t] + fred[3][t];
    __syncthreads();
    if (t < 64) {
        const float* woutT = ws + OFF_WOUTT;
        float acc = bout[t];
        #pragma unroll 16
        for (int k = 0; k < 64; ++k) acc = fmaf(fcbar_s[k], woutT[k * 64 + t], acc);
        out[(size_t)b * 64 + t] = acc;
    }
}

extern "C" void kernel_launch(void* const* d_in, const int* in_sizes, int n_in,
                              void* d_out, int out_size, void* d_ws, size_t ws_size,
                              hipStream_t stream) {
    const float* audio1 = (const float*)d_in[0];
    const float* audio2 = (const float*)d_in[1];
    const float* w1   = (const float*)d_in[2];
    const float* b1   = (const float*)d_in[3];
    const float* g1   = (const float*)d_in[4];
    const float* be1  = (const float*)d_in[5];
    const float* m1   = (const float*)d_in[6];
    const float* v1   = (const float*)d_in[7];
    const float* w2   = (const float*)d_in[8];
    const float* b2   = (const float*)d_in[9];
    const float* g2   = (const float*)d_in[10];
    const float* be2  = (const float*)d_in[11];
    const float* m2   = (const float*)d_in[12];
    const float* v2   = (const float*)d_in[13];
    const float* w3   = (const float*)d_in[14];
    const float* b3   = (const float*)d_in[15];
    const float* g3   = (const float*)d_in[16];
    const float* be3  = (const float*)d_in[17];
    const float* m3   = (const float*)d_in[18];
    const float* v3   = (const float*)d_in[19];
    const float* Wq   = (const float*)d_in[20];
    const float* bq   = (const float*)d_in[21];
    const float* Wk   = (const float*)d_in[22];
    const float* bk   = (const float*)d_in[23];
    const float* Wv   = (const float*)d_in[24];
    const float* bv   = (const float*)d_in[25];
    const float* Wfc  = (const float*)d_in[26];
    const float* bfc  = (const float*)d_in[27];
    const float* Wout = (const float*)d_in[28];
    const float* bout = (const float*)d_in[29];

    float* ws  = (float*)d_ws;
    float* out = (float*)d_out;
    int B = in_sizes[0] / SEQLEN;   // 4096
    int nseq = 2 * B;

    repack_kernel<<<536, 256, 0, stream>>>(w2, w3, Wq, Wk, Wv, Wfc, Wout, ws);
    encoder_kernel<<<nseq * 5, 256, 0, stream>>>(audio1, audio2, w1,
        b1, g1, be1, m1, v1,
        b2, g2, be2, m2, v2,
        b3, g3, be3, m3, v3,
        ws, B);
    mha_kernel<<<nseq, 256, 0, stream>>>(ws, bq, bk, bv, bfc, bout, out, B);
}

// Round 4
// 1344.024 us; speedup vs baseline: 7.4099x; 1.6067x over previous
//
#include <hip/hip_runtime.h>
#include <math.h>

#define NCHUNK 22
#define SEQLEN 600
#define BN_EPS 1e-5f
#define Y1S 164              // y1p row stride (u32), tail zeroed

// ws offsets (4-byte units)
#define OFF_W2F    0         // 16384 u32 : w2 B-frags [s16][n2][hl2][lane][r]
#define OFF_W3F    16384     // 51200 u32 : w3 B-frags [s25][nt4][hl2][lane][r]
#define OFF_WQKVF  67584     // 98304 u32 : Wqkv B-frags [h8][ks2][nt12][hl2][lane][r]
#define OFF_WFCT   165888    // 32768 f32 : Wfc transposed [j][d]
#define OFF_WOUTT  198656    // 4096  f32 : Wout transposed [k][d]
#define OFF_FEAT   202752    // 2*B*22*64 f32

typedef short bf16x8 __attribute__((ext_vector_type(8)));
typedef float f32x4 __attribute__((ext_vector_type(4)));

#if __has_builtin(__builtin_amdgcn_perm)
#define PERM_HI(r0, r1) __builtin_amdgcn_perm((r1), (r0), 0x05040100u)
#define PERM_LO(r0, r1) __builtin_amdgcn_perm((r1), (r0), 0x07060302u)
#else
#define PERM_HI(r0, r1) (((r0) & 0xFFFFu) | ((r1) << 16))
#define PERM_LO(r0, r1) (((r0) >> 16) | ((r1) & 0xFFFF0000u))
#endif

__device__ __forceinline__ float swishf(float z) {
    return z / (1.f + __expf(-z));
}
__device__ __forceinline__ unsigned short bf16_rne(float f) {
    unsigned int u = __float_as_uint(f);
    return (unsigned short)((u + 0x7FFFu + ((u >> 16) & 1u)) >> 16);
}
__device__ __forceinline__ float bf16_tof(unsigned short h) {
    return __uint_as_float(((unsigned int)h) << 16);
}
// packed u32: low16 = hi-bf16, high16 = lo-bf16 (residual)
__device__ __forceinline__ unsigned int pack_hl(float f) {
    unsigned int u = __float_as_uint(f);
    unsigned int h = (u + 0x7FFFu + ((u >> 16) & 1u)) >> 16;
    float r = f - __uint_as_float(h << 16);
    unsigned int v = __float_as_uint(r);
    unsigned int l = (v + 0x7FFFu + ((v >> 16) & 1u)) >> 16;
    return h | (l << 16);
}
__device__ __forceinline__ unsigned int frag_word(float f0, float f1, int hl) {
    unsigned short h0 = bf16_rne(f0), h1 = bf16_rne(f1);
    if (hl == 0) return (unsigned int)h0 | ((unsigned int)h1 << 16);
    unsigned short l0 = bf16_rne(f0 - bf16_tof(h0));
    unsigned short l1 = bf16_rne(f1 - bf16_tof(h1));
    return (unsigned int)l0 | ((unsigned int)l1 << 16);
}
// build hi/lo bf16x8 A-fragments from 8 packed u32 (positions p..p+7)
__device__ __forceinline__ void frag_from_packed(const unsigned int* p, bf16x8& h8, bf16x8& l8) {
    unsigned int r0 = p[0], r1 = p[1], r2 = p[2], r3 = p[3];
    unsigned int r4 = p[4], r5 = p[5], r6 = p[6], r7 = p[7];
    union U { unsigned int w[4]; bf16x8 v; } H, L;
    H.w[0] = PERM_HI(r0, r1); H.w[1] = PERM_HI(r2, r3);
    H.w[2] = PERM_HI(r4, r5); H.w[3] = PERM_HI(r6, r7);
    L.w[0] = PERM_LO(r0, r1); L.w[1] = PERM_LO(r2, r3);
    L.w[2] = PERM_LO(r4, r5); L.w[3] = PERM_LO(r6, r7);
    h8 = H.v; l8 = L.v;
}

__global__ __launch_bounds__(256) void repack_kernel(
    const float* __restrict__ w2, const float* __restrict__ w3,
    const float* __restrict__ Wq, const float* __restrict__ Wk, const float* __restrict__ Wv,
    const float* __restrict__ Wfc, const float* __restrict__ Wout,
    float* __restrict__ ws)
{
    int tid = blockIdx.x * 256 + threadIdx.x;
    unsigned int* wsu = (unsigned int*)ws;
    if (tid < 16384) {                       // w2 B-frags, K padded 416->512
        int r = tid & 3, l = (tid >> 2) & 63, hl = (tid >> 8) & 1;
        int n = (tid >> 9) & 1, s = tid >> 10;
        int co = n * 16 + (l & 15);
        int k0 = 8 * (l >> 4) + 2 * r;
        float f0 = (k0     < 26) ? w2[co * 416 + s * 26 + k0]     : 0.f;
        float f1 = (k0 + 1 < 26) ? w2[co * 416 + s * 26 + k0 + 1] : 0.f;
        wsu[OFF_W2F + tid] = frag_word(f0, f1, hl);
    }
    int t2 = tid - 16384;
    if (t2 >= 0 && t2 < 51200) {             // w3 B-frags: B[k=j][col=co], j=q*32+ci
        int r = t2 & 3, l = (t2 >> 2) & 63, hl = (t2 >> 8) & 1;
        int nt = (t2 >> 9) & 3, s = t2 >> 11;
        int co = nt * 16 + (l & 15);
        int k0 = s * 32 + (l >> 4) * 8 + 2 * r;
        float f0 = w3[co * 800 + (k0 & 31) * 25 + (k0 >> 5)];
        float f1 = w3[co * 800 + ((k0 + 1) & 31) * 25 + ((k0 + 1) >> 5)];
        wsu[OFF_W3F + t2] = frag_word(f0, f1, hl);
    }
    int t3 = tid - 67584;
    if (t3 >= 0 && t3 < 98304) {             // Wqkv B-frags: B[k=d][col=(mat,e)]
        int r = t3 & 3, l = (t3 >> 2) & 63, hl = (t3 >> 8) & 1;
        int rest = t3 >> 9;                  // 0..191
        int nt = rest % 12, rest2 = rest / 12;
        int ks = rest2 & 1, h = rest2 >> 1;
        int n = nt * 16 + (l & 15);          // 0..191
        int mat = n >> 6, e = n & 63;
        int d0 = ks * 32 + (l >> 4) * 8 + 2 * r;
        const float* W = (mat == 0) ? Wq : (mat == 1) ? Wk : Wv;
        float f0 = W[h * 4096 + e * 64 + d0];
        float f1 = W[h * 4096 + e * 64 + d0 + 1];
        wsu[OFF_WQKVF + t3] = frag_word(f0, f1, hl);
    }
    int t4 = tid - 165888;
    if (t4 >= 0 && t4 < 32768) {             // wfcT[j*64+d] = Wfc[d][j]
        int d = t4 & 63, j = t4 >> 6;
        ws[OFF_WFCT + t4] = Wfc[d * 512 + j];
    }
    int t5 = tid - 198656;
    if (t5 >= 0 && t5 < 4096) {              // woutT[k*64+d] = Wout[d][k]
        int d = t5 & 63, k = t5 >> 6;
        ws[OFF_WOUTT + t5] = Wout[d * 64 + k];
    }
}

// One block = one 5-chunk tile. conv1 fp32 -> y1p packed hi/lo; conv2 MFMA
// (bf16x3, B pre-swizzled + LDS dbuf); conv3 MFMA (1 Ntile/wave, reg prefetch).
__global__ __launch_bounds__(256, 4) void encoder_kernel(
    const float* __restrict__ audio1, const float* __restrict__ audio2,
    const float* __restrict__ w1,
    const float* __restrict__ b1, const float* __restrict__ g1, const float* __restrict__ be1,
    const float* __restrict__ m1, const float* __restrict__ v1,
    const float* __restrict__ b2, const float* __restrict__ g2, const float* __restrict__ be2,
    const float* __restrict__ m2, const float* __restrict__ v2,
    const float* __restrict__ b3, const float* __restrict__ g3, const float* __restrict__ be3,
    const float* __restrict__ m3, const float* __restrict__ v3,
    float* __restrict__ ws, int B)
{
    __shared__ float smem[9508];
    float* a_s  = smem;                              // 176
    float* w1_s = smem + 176;                        // 416
    float* A_s  = smem + 592;                        // 112
    float* Bc_s = smem + 704;                        // 112
    unsigned int* w2f = (unsigned int*)(smem + 816); // 2 x 1024 dbuf
    unsigned int* y1p = (unsigned int*)(smem + 2864);// 16 x 164 packed
    unsigned int* y2p = (unsigned int*)(smem + 5488);// 5 x 804 packed

    int t = threadIdx.x;
    int blk = blockIdx.x;
    int seq = blk / 5, tile = blk - seq * 5;
    int tc = (tile == 4) ? 2 : 5;
    int nq = 25 * tc;
    int ny1 = nq + 25;
    int na = nq + 50;
    const unsigned int* wsu = (const unsigned int*)ws;

    const float* audio = (seq < B ? audio1 + (size_t)seq * SEQLEN
                                  : audio2 + (size_t)(seq - B) * SEQLEN) + tile * 125;
    if (t < na) a_s[t] = audio[t];
    for (int i = t; i < 416; i += 256) w1_s[i] = w1[i];
    if (t < 16)       { float A = g1[t] * rsqrtf(v1[t] + BN_EPS); A_s[t] = A; Bc_s[t] = (b1[t] - m1[t]) * A + be1[t]; }
    else if (t < 48)  { int i = t - 16; float A = g2[i] * rsqrtf(v2[i] + BN_EPS); A_s[t] = A; Bc_s[t] = (b2[i] - m2[i]) * A + be2[i]; }
    else if (t < 112) { int i = t - 48; float A = g3[i] * rsqrtf(v3[i] + BN_EPS); A_s[t] = A; Bc_s[t] = (b3[i] - m3[i]) * A + be3[i]; }
    {   // stage conv2 B-frag step 0
        uint4 v = *(const uint4*)(wsu + OFF_W2F + t * 4);
        *(uint4*)(w2f + t * 4) = v;
    }
    __syncthreads();

    // ---- conv1 + bn + swish -> y1p (packed hi/lo) ----
    for (int o = t; o < ny1 * 16; o += 256) {
        int p = o >> 4, ci = o & 15;
        float acc = 0.f;
        #pragma unroll
        for (int k = 0; k < 26; ++k) acc = fmaf(a_s[p + k], w1_s[ci * 26 + k], acc);
        y1p[ci * Y1S + p] = pack_hl(swishf(fmaf(acc, A_s[ci], Bc_s[ci])));
    }
    for (int i = t; i < 16 * Y1S; i += 256) {        // zero tails
        int p = i % Y1S;
        if (p >= ny1) y1p[i] = 0u;
    }

    // ---- conv2 MFMA: 16 K-steps (ci), bf16x3 ----
    int lane = t & 63, wid = t >> 6;
    int li = lane & 15, lg = lane >> 4;
    int nmt = (nq + 15) >> 4;                        // 8 or 4
    f32x4 acc00 = {0.f,0.f,0.f,0.f}, acc01 = acc00, acc10 = acc00, acc11 = acc00;
    int base0 = wid * 16 + li + lg * 8;
    int base1 = (wid + 4) * 16 + li + lg * 8;

    for (int s = 0; s < 16; ++s) {
        __syncthreads();
        if (s < 15) {
            uint4 v = *(const uint4*)(wsu + OFF_W2F + (s + 1) * 1024 + t * 4);
            *(uint4*)(w2f + ((s + 1) & 1) * 1024 + t * 4) = v;
        }
        const unsigned int* cur = w2f + (s & 1) * 1024;
        bf16x8 bh0 = *(const bf16x8*)(cur + lane * 4);
        bf16x8 bl0 = *(const bf16x8*)(cur + 256 + lane * 4);
        bf16x8 bh1 = *(const bf16x8*)(cur + 512 + lane * 4);
        bf16x8 bl1 = *(const bf16x8*)(cur + 768 + lane * 4);
        const unsigned int* yrow = y1p + s * Y1S;
        {
            bf16x8 ah, al;
            frag_from_packed(yrow + base0, ah, al);
            acc00 = __builtin_amdgcn_mfma_f32_16x16x32_bf16(ah, bh0, acc00, 0, 0, 0);
            acc00 = __builtin_amdgcn_mfma_f32_16x16x32_bf16(al, bh0, acc00, 0, 0, 0);
            acc00 = __builtin_amdgcn_mfma_f32_16x16x32_bf16(ah, bl0, acc00, 0, 0, 0);
            acc01 = __builtin_amdgcn_mfma_f32_16x16x32_bf16(ah, bh1, acc01, 0, 0, 0);
            acc01 = __builtin_amdgcn_mfma_f32_16x16x32_bf16(al, bh1, acc01, 0, 0, 0);
            acc01 = __builtin_amdgcn_mfma_f32_16x16x32_bf16(ah, bl1, acc01, 0, 0, 0);
        }
        if (nmt == 8) {
            bf16x8 ah, al;
            frag_from_packed(yrow + base1, ah, al);
            acc10 = __builtin_amdgcn_mfma_f32_16x16x32_bf16(ah, bh0, acc10, 0, 0, 0);
            acc10 = __builtin_amdgcn_mfma_f32_16x16x32_bf16(al, bh0, acc10, 0, 0, 0);
            acc10 = __builtin_amdgcn_mfma_f32_16x16x32_bf16(ah, bl0, acc10, 0, 0, 0);
            acc11 = __builtin_amdgcn_mfma_f32_16x16x32_bf16(ah, bh1, acc11, 0, 0, 0);
            acc11 = __builtin_amdgcn_mfma_f32_16x16x32_bf16(al, bh1, acc11, 0, 0, 0);
            acc11 = __builtin_amdgcn_mfma_f32_16x16x32_bf16(ah, bl1, acc11, 0, 0, 0);
        }
    }
    // epilogue: bn + swish -> y2p packed [cc*804 + q'*32 + ci]
    {
        int co0 = 16 + li, co1 = 32 + li;
        float A0 = A_s[co0], B0 = Bc_s[co0];
        float A1 = A_s[co1], B1 = Bc_s[co1];
        #pragma unroll
        for (int r = 0; r < 4; ++r) {
            int q = wid * 16 + lg * 4 + r;
            if (q < nq) {
                int cc = q / 25, qp = q - cc * 25;
                y2p[cc * 804 + qp * 32 + li]      = pack_hl(swishf(fmaf(acc00[r], A0, B0)));
                y2p[cc * 804 + qp * 32 + 16 + li] = pack_hl(swishf(fmaf(acc01[r], A1, B1)));
            }
        }
        if (nmt == 8) {
            #pragma unroll
            for (int r = 0; r < 4; ++r) {
                int q = (wid + 4) * 16 + lg * 4 + r;
                if (q < nq) {
                    int cc = q / 25, qp = q - cc * 25;
                    y2p[cc * 804 + qp * 32 + li]      = pack_hl(swishf(fmaf(acc10[r], A0, B0)));
                    y2p[cc * 804 + qp * 32 + 16 + li] = pack_hl(swishf(fmaf(acc11[r], A1, B1)));
                }
            }
        }
    }
    __syncthreads();

    // ---- conv3 MFMA: wave wid = Ntile (16 co), M rows = chunks (tc valid) ----
    {
        const uint4* w3f4 = (const uint4*)(wsu + OFF_W3F);
        f32x4 acc3 = {0.f, 0.f, 0.f, 0.f};
        uint4 bhn = w3f4[((0 * 4 + wid) * 2 + 0) * 64 + lane];
        uint4 bln = w3f4[((0 * 4 + wid) * 2 + 1) * 64 + lane];
        for (int s = 0; s < 25; ++s) {
            uint4 bhc = bhn, blc = bln;
            if (s < 24) {
                bhn = w3f4[(((s + 1) * 4 + wid) * 2 + 0) * 64 + lane];
                bln = w3f4[(((s + 1) * 4 + wid) * 2 + 1) * 64 + lane];
            }
            bf16x8 ah = {}, al = {};
            if (li < tc) frag_from_packed(y2p + li * 804 + s * 32 + lg * 8, ah, al);
            bf16x8 bh = *(const bf16x8*)&bhc;
            bf16x8 bl = *(const bf16x8*)&blc;
            acc3 = __builtin_amdgcn_mfma_f32_16x16x32_bf16(ah, bh, acc3, 0, 0, 0);
            acc3 = __builtin_amdgcn_mfma_f32_16x16x32_bf16(al, bh, acc3, 0, 0, 0);
            acc3 = __builtin_amdgcn_mfma_f32_16x16x32_bf16(ah, bl, acc3, 0, 0, 0);
        }
        int co = wid * 16 + li;
        float A3 = A_s[48 + co], B3 = Bc_s[48 + co];
        #pragma unroll
        for (int r = 0; r < 4; ++r) {
            int cc = lg * 4 + r;
            if (cc < tc)
                ws[OFF_FEAT + ((size_t)(seq * NCHUNK + tile * 5 + cc)) * 64 + co]
                    = swishf(fmaf(acc3[r], A3, B3));
        }
    }
}

// One block per sequence. QKV via MFMA (A-frags in regs, reused all 8 heads);
// mean folded before fc (pooled attention); scores/softmax scalar.
__global__ __launch_bounds__(256, 4) void mha_kernel(
    const float* __restrict__ ws,
    const float* __restrict__ bq, const float* __restrict__ bk, const float* __restrict__ bv,
    const float* __restrict__ bfc, const float* __restrict__ bout,
    float* __restrict__ out, int B)
{
    __shared__ float smem[7760];
    unsigned int* f_p = (unsigned int*)smem;  // 32 x 68 packed (rows 22..31 zero)
    float* q_s    = smem + 2176;  // 22 x 64
    float* k_s    = smem + 3584;  // 22 x 65
    float* v_s    = smem + 5014;  // 22 x 64
    float* s_s    = smem + 6422;  // 22 x 22
    float* abar_s = smem + 6906;  // 22
    float* obar_s = smem + 6928;  // 8 x 64
    float* fred   = smem + 7440;  // 4 x 64
    float* fcbar_s= smem + 7696;  // 64

    int t = threadIdx.x, b = blockIdx.x;
    int lane = t & 63, wid = t >> 6;
    int li = lane & 15, lg = lane >> 4;
    const float* feat = ws + OFF_FEAT + (size_t)b * 1408;
    for (int i = t; i < 1408; i += 256) {
        int s = i >> 6, d = i & 63;
        f_p[s * 68 + d] = pack_hl(feat[i]);
    }
    for (int i = 1496 + t; i < 2176; i += 256) f_p[i] = 0u;
    __syncthreads();

    // A-frags once: F[row][d], rows mt*16+li, k = ks*32+lg*8+e
    bf16x8 fah[2][2], fal[2][2];
    #pragma unroll
    for (int mt = 0; mt < 2; ++mt)
        #pragma unroll
        for (int ks = 0; ks < 2; ++ks)
            frag_from_packed(f_p + (mt * 16 + li) * 68 + ks * 32 + lg * 8,
                             fah[mt][ks], fal[mt][ks]);

    const uint4* wqkvf4 = (const uint4*)((const unsigned int*)ws + OFF_WQKVF);

    for (int h = 0; h < 8; ++h) {
        // QKV MFMA: wave handles nt = wid*3 + {0,1,2} of 12 (Q:0-3, K:4-7, V:8-11)
        for (int j = 0; j < 3; ++j) {
            int nt = wid * 3 + j;
            f32x4 a0 = {0.f,0.f,0.f,0.f}, a1 = a0;
            #pragma unroll
            for (int ks = 0; ks < 2; ++ks) {
                uint4 bh4 = wqkvf4[(((h * 2 + ks) * 12 + nt) * 2 + 0) * 64 + lane];
                uint4 bl4 = wqkvf4[(((h * 2 + ks) * 12 + nt) * 2 + 1) * 64 + lane];
                bf16x8 bh = *(const bf16x8*)&bh4;
                bf16x8 bl = *(const bf16x8*)&bl4;
                a0 = __builtin_amdgcn_mfma_f32_16x16x32_bf16(fah[0][ks], bh, a0, 0, 0, 0);
                a0 = __builtin_amdgcn_mfma_f32_16x16x32_bf16(fal[0][ks], bh, a0, 0, 0, 0);
                a0 = __builtin_amdgcn_mfma_f32_16x16x32_bf16(fah[0][ks], bl, a0, 0, 0, 0);
                a1 = __builtin_amdgcn_mfma_f32_16x16x32_bf16(fah[1][ks], bh, a1, 0, 0, 0);
                a1 = __builtin_amdgcn_mfma_f32_16x16x32_bf16(fal[1][ks], bh, a1, 0, 0, 0);
                a1 = __builtin_amdgcn_mfma_f32_16x16x32_bf16(fah[1][ks], bl, a1, 0, 0, 0);
            }
            int mat = nt >> 2;
            int e = (nt & 3) * 16 + li;
            float* dst; int stride; float bias;
            if (mat == 0)      { dst = q_s; stride = 64; bias = bq[h * 64 + e]; }
            else if (mat == 1) { dst = k_s; stride = 65; bias = bk[h * 64 + e]; }
            else               { dst = v_s; stride = 64; bias = bv[h * 64 + e]; }
            #pragma unroll
            for (int r = 0; r < 4; ++r) {
                int row0 = lg * 4 + r;
                dst[row0 * stride + e] = a0[r] + bias;
                int row1 = 16 + row0;
                if (row1 < 22) dst[row1 * stride + e] = a1[r] + bias;
            }
        }
        __syncthreads();
        // scores S = Q K^T
        for (int o = t; o < 484; o += 256) {
            int s = o / 22, u = o - s * 22;
            float acc = 0.f;
            #pragma unroll 16
            for (int d = 0; d < 64; ++d) acc = fmaf(q_s[s * 64 + d], k_s[u * 65 + d], acc);
            s_s[s * 22 + u] = acc;
        }
        __syncthreads();
        if (t < 22) {   // softmax row t
            float m = -1e30f;
            #pragma unroll
            for (int j2 = 0; j2 < 22; ++j2) m = fmaxf(m, s_s[t * 22 + j2]);
            float sum = 0.f;
            #pragma unroll
            for (int j2 = 0; j2 < 22; ++j2) { float ev = __expf(s_s[t * 22 + j2] - m); s_s[t * 22 + j2] = ev; sum += ev; }
            float rr = 1.f / sum;
            #pragma unroll
            for (int j2 = 0; j2 < 22; ++j2) s_s[t * 22 + j2] *= rr;
        }
        __syncthreads();
        if (t < 22) {   // column means of A
            float a = 0.f;
            #pragma unroll
            for (int s = 0; s < 22; ++s) a += s_s[s * 22 + t];
            abar_s[t] = a * (1.f / 22.f);
        }
        __syncthreads();
        if (t < 64) {   // pooled O for this head
            float acc = 0.f;
            #pragma unroll
            for (int u = 0; u < 22; ++u) acc = fmaf(abar_s[u], v_s[u * 64 + t], acc);
            obar_s[h * 64 + t] = acc;
        }
        __syncthreads();
    }
    // fcbar = obar(512) @ WfcT + bfc, split over 4 waves
    {
        int d = t & 63, part = t >> 6;
        const float* wfc = ws + OFF_WFCT + d;
        float acc = 0.f;
        for (int j = part * 128; j < part * 128 + 128; ++j)
            acc = fmaf(obar_s[j], wfc[j * 64], acc);
        fred[part * 64 + d] = acc;
    }
    __syncthreads();
    if (t < 64) fcbar_s[t] = bfc[t] + fred[t] + fred[64 + t] + fred[128 + t] + fred[192 + t];
    __syncthreads();
    if (t < 64) {
        const float* woutT = ws + OFF_WOUTT;
        float acc = bout[t];
        #pragma unroll 16
        for (int k = 0; k < 64; ++k) acc = fmaf(fcbar_s[k], woutT[k * 64 + t], acc);
        out[(size_t)b * 64 + t] = acc;
    }
}

extern "C" void kernel_launch(void* const* d_in, const int* in_sizes, int n_in,
                              void* d_out, int out_size, void* d_ws, size_t ws_size,
                              hipStream_t stream) {
    const float* audio1 = (const float*)d_in[0];
    const float* audio2 = (const float*)d_in[1];
    const float* w1   = (const float*)d_in[2];
    const float* b1   = (const float*)d_in[3];
    const float* g1   = (const float*)d_in[4];
    const float* be1  = (const float*)d_in[5];
    const float* m1   = (const float*)d_in[6];
    const float* v1   = (const float*)d_in[7];
    const float* w2   = (const float*)d_in[8];
    const float* b2   = (const float*)d_in[9];
    const float* g2   = (const float*)d_in[10];
    const float* be2  = (const float*)d_in[11];
    const float* m2   = (const float*)d_in[12];
    const float* v2   = (const float*)d_in[13];
    const float* w3   = (const float*)d_in[14];
    const float* b3   = (const float*)d_in[15];
    const float* g3   = (const float*)d_in[16];
    const float* be3  = (const float*)d_in[17];
    const float* m3   = (const float*)d_in[18];
    const float* v3   = (const float*)d_in[19];
    const float* Wq   = (const float*)d_in[20];
    const float* bq   = (const float*)d_in[21];
    const float* Wk   = (const float*)d_in[22];
    const float* bk   = (const float*)d_in[23];
    const float* Wv   = (const float*)d_in[24];
    const float* bv   = (const float*)d_in[25];
    const float* Wfc  = (const float*)d_in[26];
    const float* bfc  = (const float*)d_in[27];
    const float* Wout = (const float*)d_in[28];
    const float* bout = (const float*)d_in[29];

    float* ws  = (float*)d_ws;
    float* out = (float*)d_out;
    int B = in_sizes[0] / SEQLEN;   // 4096
    int nseq = 2 * B;

    repack_kernel<<<792, 256, 0, stream>>>(w2, w3, Wq, Wk, Wv, Wfc, Wout, ws);
    encoder_kernel<<<nseq * 5, 256, 0, stream>>>(audio1, audio2, w1,
        b1, g1, be1, m1, v1,
        b2, g2, be2, m2, v2,
        b3, g3, be3, m3, v3,
        ws, B);
    mha_kernel<<<nseq, 256, 0, stream>>>(ws, bq, bk, bv, bfc, bout, out, B);
}